// Round 1
// baseline (686.480 us; speedup 1.0000x reference)
//
#include <hip/hip_runtime.h>
#include <math.h>

constexpr int kN  = 4096;
constexpr int kFI = 128;
constexpr int kFO = 64;
constexpr int kH  = 4;
constexpr int kHF = 256;   // kH*kFO
constexpr float kNegInf = -1e9f;
constexpr float kLnEps  = 1e-5f;

__device__ __forceinline__ float lrelu(float x){ return x >= 0.f ? x : 0.2f*x; }

__device__ __forceinline__ float wave_sum(float v){
  #pragma unroll
  for (int s = 32; s > 0; s >>= 1) v += __shfl_xor(v, s, 64);
  return v;
}

// ---------------------------------------------------------------------------
// K1: proj[h][n][o], a[h][n]=proj·score_src, b[h][n]=proj·score_tgt,
//     skip[n][h*64+o] = nodes @ skip_w^T.   One block = 16 nodes, 256 thr.
// ---------------------------------------------------------------------------
__global__ __launch_bounds__(256) void k_proj(
    const float* __restrict__ nodes, const float* __restrict__ pp,
    const float* __restrict__ ssrc,  const float* __restrict__ stgt,
    const float* __restrict__ skw,
    float* __restrict__ proj, float* __restrict__ ga, float* __restrict__ gb,
    float* __restrict__ skipo)
{
  __shared__ float feat[16][kFI];           // 8 KB
  const int tid = threadIdx.x;
  const int n0  = blockIdx.x * 16;
  for (int idx = tid; idx < 16*kFI; idx += 256)
    feat[idx >> 7][idx & 127] = nodes[n0*kFI + idx];
  __syncthreads();
  const int h = tid >> 6, o = tid & 63;
  float accP[16], accS[16];
  #pragma unroll
  for (int n = 0; n < 16; ++n){ accP[n] = 0.f; accS[n] = 0.f; }
  for (int k = 0; k < kFI; ++k){
    const float p = pp[(h*kFI + k)*kFO + o];
    const float w = skw[tid*kFI + k];
    #pragma unroll
    for (int n = 0; n < 16; ++n){
      const float f = feat[n][k];
      accP[n] = fmaf(f, p, accP[n]);
      accS[n] = fmaf(f, w, accS[n]);
    }
  }
  const float sa = ssrc[h*kFO + o];
  const float sb = stgt[h*kFO + o];
  #pragma unroll
  for (int n = 0; n < 16; ++n){
    proj[(h*kN + n0+n)*kFO + o] = accP[n];
    skipo[(n0+n)*kHF + tid]     = accS[n];
    const float va = wave_sum(accP[n] * sa);
    const float vb = wave_sum(accP[n] * sb);
    if (o == 0){ ga[h*kN + n0+n] = va; gb[h*kN + n0+n] = vb; }
  }
}

// ---------------------------------------------------------------------------
// K2: column pass. mask from degree+bond, S[h][j] = sum_i exp(score+mask)
// (unstabilized — safe, see analysis). Optionally stores mask to ws.
// grid (16 j-tiles, 32 i-strips) x 256 threads.
// ---------------------------------------------------------------------------
__global__ __launch_bounds__(256) void k_colsum(
    const float* __restrict__ degm, const float* __restrict__ bondm,
    const float* __restrict__ ga,   const float* __restrict__ gb,
    const int* __restrict__ cutp,
    float* __restrict__ S, float* __restrict__ maskws, int write_mask)
{
  const int j = blockIdx.x * 256 + threadIdx.x;
  const float cut = (float)cutp[0];
  const float b0 = gb[0*kN + j], b1 = gb[1*kN + j];
  const float b2 = gb[2*kN + j], b3 = gb[3*kN + j];
  float s0 = 0.f, s1 = 0.f, s2 = 0.f, s3 = 0.f;
  const int i0 = blockIdx.y * (kN/32);
  for (int i = i0; i < i0 + kN/32; ++i){
    const float dg  = degm[i*kN + j];
    const float bd  = bondm[i*kN + j];
    const float wdm = dg + bd;
    const float m = wdm > 0.f ? wdm : (bd > cut ? bd + wdm : kNegInf);
    if (write_mask) maskws[i*kN + j] = m;
    const float a0 = ga[0*kN + i], a1 = ga[1*kN + i];
    const float a2 = ga[2*kN + i], a3 = ga[3*kN + i];
    s0 += __expf(lrelu(a0 + b0) + m);
    s1 += __expf(lrelu(a1 + b1) + m);
    s2 += __expf(lrelu(a2 + b2) + m);
    s3 += __expf(lrelu(a3 + b3) + m);
  }
  atomicAdd(&S[0*kN + j], s0);
  atomicAdd(&S[1*kN + j], s1);
  atomicAdd(&S[2*kN + j], s2);
  atomicAdd(&S[3*kN + j], s3);
}

// ---------------------------------------------------------------------------
// K2b: fold 1/S into proj in place: pS[h][j][f] = proj[h][j][f] / S[h][j]
// ---------------------------------------------------------------------------
__global__ __launch_bounds__(256) void k_ps(
    float* __restrict__ proj, const float* __restrict__ S)
{
  const int idx = blockIdx.x * 256 + threadIdx.x;   // over H*N*FO
  proj[idx] = proj[idx] / S[idx >> 6];
}

// ---------------------------------------------------------------------------
// K3: row pass. Per block: 16 rows. 512 threads = two 256-thread halves, each
// owning one j-half (2048 cols) in chunks of 64.
//  phase A: compute e=exp(leaky(a+b)+m) into LDS + accumulate row sum/sumsq
//  phase B: acc[h,i,f] += e * pS  (LDS same-address broadcast reads, float4)
//  epilogue: merge halves, out = elu(acc+skip), mask_ln = (m-mu)*rsig
// ---------------------------------------------------------------------------
__global__ __launch_bounds__(512) void k_aggr(
    const float* __restrict__ degm, const float* __restrict__ bondm,
    const float* __restrict__ maskws, int have_mask,
    const float* __restrict__ ga, const float* __restrict__ gb,
    const int* __restrict__ cutp,
    const float* __restrict__ pS, const float* __restrict__ skipo,
    float* __restrict__ outp, float* __restrict__ mlnp)
{
  constexpr int R = 16, JC = 64;
  __shared__ __align__(16) float wl[2][kH][R][JC];   // 32 KB
  __shared__ float rs[2][R][2];
  __shared__ float stats[R][2];
  const int tid   = threadIdx.x;
  const int jhalf = tid >> 8;
  const int t     = tid & 255;
  const int w     = t >> 6;        // wave-in-half; doubles as head in phase B
  const int lane  = t & 63;
  const int r0    = blockIdx.x * R;
  const float cut = (float)cutp[0];

  if (tid < 2*R*2) ((float*)rs)[tid] = 0.f;

  float av[4][kH];
  #pragma unroll
  for (int k = 0; k < 4; ++k){
    const int i = w + 4*k;
    #pragma unroll
    for (int h = 0; h < kH; ++h) av[k][h] = ga[h*kN + r0 + i];
  }

  float acc[R];
  #pragma unroll
  for (int i = 0; i < R; ++i) acc[i] = 0.f;

  __syncthreads();

  for (int c = 0; c < 32; ++c){
    const int jbase = jhalf*2048 + c*JC;
    // ---- phase A ----
    {
      const int jg = jbase + lane;
      float bv[kH];
      #pragma unroll
      for (int h = 0; h < kH; ++h) bv[h] = gb[h*kN + jg];
      #pragma unroll
      for (int k = 0; k < 4; ++k){
        const int i = w + 4*k;
        float m;
        if (have_mask){
          m = maskws[(r0+i)*kN + jg];
        } else {
          const float dg  = degm[(r0+i)*kN + jg];
          const float bd  = bondm[(r0+i)*kN + jg];
          const float wdm = dg + bd;
          m = wdm > 0.f ? wdm : (bd > cut ? bd + wdm : kNegInf);
        }
        const float s1 = wave_sum(m);
        const float s2 = wave_sum(m*m);
        if (lane == 0){ rs[jhalf][i][0] += s1; rs[jhalf][i][1] += s2; }
        #pragma unroll
        for (int h = 0; h < kH; ++h)
          wl[jhalf][h][i][lane] = __expf(lrelu(av[k][h] + bv[h]) + m);
      }
    }
    __syncthreads();
    // ---- phase B ----
    {
      const int f = lane;
      #pragma unroll
      for (int q = 0; q < 16; ++q){
        const int jg = jbase + q*4;
        const float p0 = pS[(w*kN + jg+0)*kFO + f];
        const float p1 = pS[(w*kN + jg+1)*kFO + f];
        const float p2 = pS[(w*kN + jg+2)*kFO + f];
        const float p3 = pS[(w*kN + jg+3)*kFO + f];
        #pragma unroll
        for (int i = 0; i < R; ++i){
          const float4 w4 = *((const float4*)&wl[jhalf][w][i][q*4]);
          acc[i] = fmaf(w4.x, p0, fmaf(w4.y, p1,
                   fmaf(w4.z, p2, fmaf(w4.w, p3, acc[i]))));
        }
      }
    }
    __syncthreads();
  }

  // merge the two j-halves
  float* mbuf = (float*)wl;
  if (jhalf == 1){
    #pragma unroll
    for (int i = 0; i < R; ++i) mbuf[t*R + i] = acc[i];
  }
  __syncthreads();
  if (jhalf == 0){
    #pragma unroll
    for (int i = 0; i < R; ++i) acc[i] += mbuf[t*R + i];
  }
  if (tid < R){
    const float sum = rs[0][tid][0] + rs[1][tid][0];
    const float sq  = rs[0][tid][1] + rs[1][tid][1];
    const float mu  = sum * (1.f/kN);
    const float var = sq * (1.f/kN) - mu*mu;
    stats[tid][0] = mu;
    stats[tid][1] = rsqrtf(var + kLnEps);
  }
  __syncthreads();

  if (jhalf == 0){
    #pragma unroll
    for (int i = 0; i < R; ++i){
      float o = acc[i] + skipo[(r0+i)*kHF + t];
      o = o > 0.f ? o : expm1f(o);
      outp[(r0+i)*kHF + t] = o;
    }
  }

  for (int idx = tid; idx < R*kN; idx += 512){
    const int i = idx >> 12;
    const int j = idx & (kN - 1);
    float m;
    if (have_mask){
      m = maskws[(r0+i)*kN + j];
    } else {
      const float dg  = degm[(r0+i)*kN + j];
      const float bd  = bondm[(r0+i)*kN + j];
      const float wdm = dg + bd;
      m = wdm > 0.f ? wdm : (bd > cut ? bd + wdm : kNegInf);
    }
    mlnp[(r0+i)*kN + j] = (m - stats[i][0]) * stats[i][1];
  }
}

// ---------------------------------------------------------------------------
extern "C" void kernel_launch(void* const* d_in, const int* in_sizes, int n_in,
                              void* d_out, int out_size, void* d_ws, size_t ws_size,
                              hipStream_t stream)
{
  const float* nodes = (const float*)d_in[0];
  const float* degm  = (const float*)d_in[1];
  // d_in[2] (edges_features_distance) unused by the reference
  const float* bondm = (const float*)d_in[3];
  const float* pp    = (const float*)d_in[4];
  const float* ssrc  = (const float*)d_in[5];
  const float* stgt  = (const float*)d_in[6];
  const float* skw   = (const float*)d_in[7];
  const int*   cutp  = (const int*)d_in[8];

  float* ws   = (float*)d_ws;
  float* proj = ws;                               // H*N*FO (becomes pS)
  float* ga   = proj + (size_t)kH*kN*kFO;         // H*N
  float* gb   = ga + kH*kN;                       // H*N
  float* S    = gb + kH*kN;                       // H*N
  float* skip = S + kH*kN;                        // N*HF
  float* mask = skip + (size_t)kN*kHF;            // N*N (optional)

  const size_t base_floats = (size_t)kH*kN*kFO + 3*(size_t)kH*kN + (size_t)kN*kHF;
  const size_t need_mask   = (base_floats + (size_t)kN*kN) * sizeof(float);
  const int have_mask = (ws_size >= need_mask) ? 1 : 0;

  float* outp = (float*)d_out;
  float* mlnp = outp + (size_t)kN*kHF;

  hipMemsetAsync(S, 0, kH*kN*sizeof(float), stream);
  k_proj<<<kN/16, 256, 0, stream>>>(nodes, pp, ssrc, stgt, skw, proj, ga, gb, skip);
  k_colsum<<<dim3(kN/256, 32), 256, 0, stream>>>(degm, bondm, ga, gb, cutp, S, mask, have_mask);
  k_ps<<<(kH*kN*kFO)/256, 256, 0, stream>>>(proj, S);
  k_aggr<<<kN/16, 512, 0, stream>>>(degm, bondm, mask, have_mask, ga, gb, cutp,
                                    proj, skip, outp, mlnp);
}

// Round 2
// 523.017 us; speedup vs baseline: 1.3125x; 1.3125x over previous
//
#include <hip/hip_runtime.h>
#include <math.h>

constexpr int kN  = 4096;
constexpr int kFI = 128;
constexpr int kFO = 64;
constexpr int kH  = 4;
constexpr int kHF = 256;   // kH*kFO
constexpr float kNegInf = -1e9f;
constexpr float kLnEps  = 1e-5f;

__device__ __forceinline__ float lrelu(float x){ return x >= 0.f ? x : 0.2f*x; }

__device__ __forceinline__ float wave_sum(float v){
  #pragma unroll
  for (int s = 32; s > 0; s >>= 1) v += __shfl_xor(v, s, 64);
  return v;
}

// ---------------------------------------------------------------------------
// K1: proj[h][n][o], ga/gb scores, skip = nodes @ skip_w^T. 16 nodes/block.
// ---------------------------------------------------------------------------
__global__ __launch_bounds__(256) void k_proj(
    const float* __restrict__ nodes, const float* __restrict__ pp,
    const float* __restrict__ ssrc,  const float* __restrict__ stgt,
    const float* __restrict__ skw,
    float* __restrict__ proj, float* __restrict__ ga, float* __restrict__ gb,
    float* __restrict__ skipo)
{
  __shared__ float feat[16][kFI];
  const int tid = threadIdx.x;
  const int n0  = blockIdx.x * 16;
  for (int idx = tid; idx < 16*kFI; idx += 256)
    feat[idx >> 7][idx & 127] = nodes[n0*kFI + idx];
  __syncthreads();
  const int h = tid >> 6, o = tid & 63;
  float accP[16], accS[16];
  #pragma unroll
  for (int n = 0; n < 16; ++n){ accP[n] = 0.f; accS[n] = 0.f; }
  for (int k = 0; k < kFI; ++k){
    const float p = pp[(h*kFI + k)*kFO + o];
    const float w = skw[tid*kFI + k];
    #pragma unroll
    for (int n = 0; n < 16; ++n){
      const float f = feat[n][k];
      accP[n] = fmaf(f, p, accP[n]);
      accS[n] = fmaf(f, w, accS[n]);
    }
  }
  const float sa = ssrc[h*kFO + o];
  const float sb = stgt[h*kFO + o];
  #pragma unroll
  for (int n = 0; n < 16; ++n){
    proj[(h*kN + n0+n)*kFO + o] = accP[n];
    skipo[(n0+n)*kHF + tid]     = accS[n];
    const float va = wave_sum(accP[n] * sa);
    const float vb = wave_sum(accP[n] * sb);
    if (o == 0){ ga[h*kN + n0+n] = va; gb[h*kN + n0+n] = vb; }
  }
}

// ---------------------------------------------------------------------------
// K2: column pass, float4 over j. grid (kN/1024, 128 strips) x 256 thr.
// S[h][j] = sum_i exp(leaky(a_i+b_j)+mask_ij), unstabilized (safe: scores
// bounded; -1e9 entries underflow to 0 exactly like the stabilized ref).
// ---------------------------------------------------------------------------
__global__ __launch_bounds__(256) void k_colsum(
    const float* __restrict__ degm, const float* __restrict__ bondm,
    const float* __restrict__ ga,   const float* __restrict__ gb,
    const int* __restrict__ cutp,
    float* __restrict__ S, float* __restrict__ maskws, int write_mask)
{
  const int j0 = (blockIdx.x * 256 + threadIdx.x) * 4;
  const float cut = (float)cutp[0];
  float4 bv[kH], sv[kH];
  #pragma unroll
  for (int h = 0; h < kH; ++h){
    bv[h] = *(const float4*)&gb[h*kN + j0];
    sv[h] = make_float4(0.f, 0.f, 0.f, 0.f);
  }
  const int i0 = blockIdx.y * (kN/128);
  for (int i = i0; i < i0 + kN/128; ++i){
    const float4 dg = *(const float4*)&degm[i*kN + j0];
    const float4 bd = *(const float4*)&bondm[i*kN + j0];
    float4 m;
    {
      float w0 = dg.x + bd.x, w1 = dg.y + bd.y, w2 = dg.z + bd.z, w3 = dg.w + bd.w;
      m.x = w0 > 0.f ? w0 : (bd.x > cut ? bd.x + w0 : kNegInf);
      m.y = w1 > 0.f ? w1 : (bd.y > cut ? bd.y + w1 : kNegInf);
      m.z = w2 > 0.f ? w2 : (bd.z > cut ? bd.z + w2 : kNegInf);
      m.w = w3 > 0.f ? w3 : (bd.w > cut ? bd.w + w3 : kNegInf);
    }
    if (write_mask) *(float4*)&maskws[i*kN + j0] = m;
    #pragma unroll
    for (int h = 0; h < kH; ++h){
      const float a = ga[h*kN + i];
      sv[h].x += __expf(lrelu(a + bv[h].x) + m.x);
      sv[h].y += __expf(lrelu(a + bv[h].y) + m.y);
      sv[h].z += __expf(lrelu(a + bv[h].z) + m.z);
      sv[h].w += __expf(lrelu(a + bv[h].w) + m.w);
    }
  }
  #pragma unroll
  for (int h = 0; h < kH; ++h){
    atomicAdd(&S[h*kN + j0+0], sv[h].x);
    atomicAdd(&S[h*kN + j0+1], sv[h].y);
    atomicAdd(&S[h*kN + j0+2], sv[h].z);
    atomicAdd(&S[h*kN + j0+3], sv[h].w);
  }
}

// ---------------------------------------------------------------------------
// K2b: fold 1/S into proj in place.
// ---------------------------------------------------------------------------
__global__ __launch_bounds__(256) void k_ps(
    float* __restrict__ proj, const float* __restrict__ S)
{
  const int idx = blockIdx.x * 256 + threadIdx.x;
  proj[idx] = proj[idx] / S[idx >> 6];
}

// ---------------------------------------------------------------------------
// K3: aggregation. grid (kN/16 row-groups, 4 j-quarters) x 512 threads.
// Per chunk of 64 cols: phase A computes e=exp(leaky(a+b)+m) into LDS
// (+ local mask stats), phase B does acc[h,i,f] += e * pS via LDS-broadcast
// float4 reads. Partial acc merged by global atomics; stats by atomics.
// ---------------------------------------------------------------------------
__global__ __launch_bounds__(512) void k_aggr(
    const float* __restrict__ degm, const float* __restrict__ bondm,
    const float* __restrict__ maskws, int have_mask,
    const float* __restrict__ ga, const float* __restrict__ gb,
    const int* __restrict__ cutp,
    const float* __restrict__ pS,
    float* __restrict__ accg, float* __restrict__ statg)
{
  constexpr int R = 16, JC = 64;
  __shared__ __align__(16) float wl[kH][R][JC];   // 16 KB
  const int tid  = threadIdx.x;
  const int w    = tid >> 6;        // 0..7
  const int lane = tid & 63;
  const int r0   = blockIdx.x * R;
  const int jq0  = blockIdx.y * (kN/4);
  const float cut = (float)cutp[0];

  // phase A rows for this thread: i = w + 8k, k=0..1
  float av[2][kH];
  #pragma unroll
  for (int k = 0; k < 2; ++k)
    #pragma unroll
    for (int h = 0; h < kH; ++h) av[k][h] = ga[h*kN + r0 + w + 8*k];

  // phase B assignment
  const int hb = w & 3;
  const int rb = (w >> 2) * 8;

  float acc[8];
  #pragma unroll
  for (int i = 0; i < 8; ++i) acc[i] = 0.f;
  float msum[2] = {0.f, 0.f}, msq[2] = {0.f, 0.f};

  for (int c = 0; c < (kN/4)/JC; ++c){
    const int jbase = jq0 + c*JC;
    // ---- phase A ----
    {
      const int jg = jbase + lane;
      float bv[kH];
      #pragma unroll
      for (int h = 0; h < kH; ++h) bv[h] = gb[h*kN + jg];
      #pragma unroll
      for (int k = 0; k < 2; ++k){
        const int i = w + 8*k;
        float m;
        if (have_mask){
          m = maskws[(size_t)(r0+i)*kN + jg];
        } else {
          const float dg  = degm[(size_t)(r0+i)*kN + jg];
          const float bd  = bondm[(size_t)(r0+i)*kN + jg];
          const float wdm = dg + bd;
          m = wdm > 0.f ? wdm : (bd > cut ? bd + wdm : kNegInf);
        }
        msum[k] += m; msq[k] += m*m;
        #pragma unroll
        for (int h = 0; h < kH; ++h)
          wl[h][i][lane] = __expf(lrelu(av[k][h] + bv[h]) + m);
      }
    }
    __syncthreads();
    // ---- phase B ----
    {
      #pragma unroll
      for (int q = 0; q < 16; ++q){
        const int j = jbase + q*4;
        const float p0 = pS[(size_t)(hb*kN + j+0)*kFO + lane];
        const float p1 = pS[(size_t)(hb*kN + j+1)*kFO + lane];
        const float p2 = pS[(size_t)(hb*kN + j+2)*kFO + lane];
        const float p3 = pS[(size_t)(hb*kN + j+3)*kFO + lane];
        #pragma unroll
        for (int i = 0; i < 8; ++i){
          const float4 e = *((const float4*)&wl[hb][rb+i][q*4]);
          acc[i] = fmaf(e.x, p0, fmaf(e.y, p1,
                   fmaf(e.z, p2, fmaf(e.w, p3, acc[i]))));
        }
      }
    }
    __syncthreads();
  }

  #pragma unroll
  for (int i = 0; i < 8; ++i)
    atomicAdd(&accg[(size_t)(r0+rb+i)*kHF + hb*kFO + lane], acc[i]);

  #pragma unroll
  for (int k = 0; k < 2; ++k){
    const float s1 = wave_sum(msum[k]);
    const float s2 = wave_sum(msq[k]);
    if (lane == 0){
      atomicAdd(&statg[2*(r0 + w + 8*k) + 0], s1);
      atomicAdd(&statg[2*(r0 + w + 8*k) + 1], s2);
    }
  }
}

// ---------------------------------------------------------------------------
// K4: out = elu(acc + skip)
// ---------------------------------------------------------------------------
__global__ __launch_bounds__(256) void k_out(
    const float* __restrict__ accg, const float* __restrict__ skipo,
    float* __restrict__ outp)
{
  const int idx = blockIdx.x * 256 + threadIdx.x;
  float o = accg[idx] + skipo[idx];
  o = o > 0.f ? o : expm1f(o);
  outp[idx] = o;
}

// ---------------------------------------------------------------------------
// K5: mask_ln = (m - mu) * rsqrt(var + eps), float4 over j.
// ---------------------------------------------------------------------------
__global__ __launch_bounds__(256) void k_mln(
    const float* __restrict__ degm, const float* __restrict__ bondm,
    const float* __restrict__ maskws, int have_mask,
    const int* __restrict__ cutp,
    const float* __restrict__ statg, float* __restrict__ mlnp)
{
  const int idx = blockIdx.x * 256 + threadIdx.x;   // over kN*kN/4
  const int i = idx >> 10;                          // kN/4 float4 per row
  const float mu   = statg[2*i] * (1.f/kN);
  const float var  = statg[2*i+1] * (1.f/kN) - mu*mu;
  const float rsig = rsqrtf(var + kLnEps);
  float4 m;
  if (have_mask){
    m = ((const float4*)maskws)[idx];
  } else {
    const float cut = (float)cutp[0];
    const float4 dg = ((const float4*)degm)[idx];
    const float4 bd = ((const float4*)bondm)[idx];
    float w0 = dg.x + bd.x, w1 = dg.y + bd.y, w2 = dg.z + bd.z, w3 = dg.w + bd.w;
    m.x = w0 > 0.f ? w0 : (bd.x > cut ? bd.x + w0 : kNegInf);
    m.y = w1 > 0.f ? w1 : (bd.y > cut ? bd.y + w1 : kNegInf);
    m.z = w2 > 0.f ? w2 : (bd.z > cut ? bd.z + w2 : kNegInf);
    m.w = w3 > 0.f ? w3 : (bd.w > cut ? bd.w + w3 : kNegInf);
  }
  float4 o;
  o.x = (m.x - mu) * rsig;  o.y = (m.y - mu) * rsig;
  o.z = (m.z - mu) * rsig;  o.w = (m.w - mu) * rsig;
  ((float4*)mlnp)[idx] = o;
}

// ---------------------------------------------------------------------------
extern "C" void kernel_launch(void* const* d_in, const int* in_sizes, int n_in,
                              void* d_out, int out_size, void* d_ws, size_t ws_size,
                              hipStream_t stream)
{
  const float* nodes = (const float*)d_in[0];
  const float* degm  = (const float*)d_in[1];
  const float* bondm = (const float*)d_in[3];
  const float* pp    = (const float*)d_in[4];
  const float* ssrc  = (const float*)d_in[5];
  const float* stgt  = (const float*)d_in[6];
  const float* skw   = (const float*)d_in[7];
  const int*   cutp  = (const int*)d_in[8];

  float* ws   = (float*)d_ws;
  float* proj = ws;                               // H*N*FO (becomes pS)
  float* ga   = proj + (size_t)kH*kN*kFO;         // H*N
  float* gb   = ga + kH*kN;                       // H*N
  float* S    = gb + kH*kN;                       // H*N
  float* skip = S + kH*kN;                        // N*HF
  float* accg = skip + (size_t)kN*kHF;            // N*HF
  float* statg= accg + (size_t)kN*kHF;            // 2*N
  float* mask = statg + 2*kN;                     // N*N (optional)

  const size_t base_floats = (size_t)kH*kN*kFO + 3*(size_t)kH*kN
                           + 2*(size_t)kN*kHF + 2*kN;
  const size_t need_mask   = (base_floats + (size_t)kN*kN) * sizeof(float);
  const int have_mask = (ws_size >= need_mask) ? 1 : 0;

  float* outp = (float*)d_out;
  float* mlnp = outp + (size_t)kN*kHF;

  hipMemsetAsync(S, 0, kH*kN*sizeof(float), stream);
  hipMemsetAsync(accg, 0, (size_t)kN*kHF*sizeof(float), stream);
  hipMemsetAsync(statg, 0, 2*kN*sizeof(float), stream);

  k_proj<<<kN/16, 256, 0, stream>>>(nodes, pp, ssrc, stgt, skw, proj, ga, gb, skip);
  k_colsum<<<dim3(kN/1024, 128), 256, 0, stream>>>(degm, bondm, ga, gb, cutp,
                                                   S, mask, have_mask);
  k_ps<<<(kH*kN*kFO)/256, 256, 0, stream>>>(proj, S);
  k_aggr<<<dim3(kN/16, 4), 512, 0, stream>>>(degm, bondm, mask, have_mask,
                                             ga, gb, cutp, proj, accg, statg);
  k_out<<<(kN*kHF)/256, 256, 0, stream>>>(accg, skip, outp);
  k_mln<<<(kN*(kN/4))/256, 256, 0, stream>>>(degm, bondm, mask, have_mask,
                                             cutp, statg, mlnp);
}

// Round 3
// 365.333 us; speedup vs baseline: 1.8791x; 1.4316x over previous
//
#include <hip/hip_runtime.h>
#include <math.h>

constexpr int kN  = 4096;
constexpr int kFI = 128;
constexpr int kFO = 64;
constexpr int kH  = 4;
constexpr int kHF = 256;   // kH*kFO
constexpr float kNegInf = -1e9f;
constexpr float kLnEps  = 1e-5f;

typedef short bf16x8 __attribute__((ext_vector_type(8)));
typedef float f32x4  __attribute__((ext_vector_type(4)));

__device__ __forceinline__ float lrelu(float x){ return x >= 0.f ? x : 0.2f*x; }

__device__ __forceinline__ float wave_sum(float v){
  #pragma unroll
  for (int s = 32; s > 0; s >>= 1) v += __shfl_xor(v, s, 64);
  return v;
}

__device__ __forceinline__ unsigned short f2bf(float x){
  unsigned u = __float_as_uint(x);
  u = (u + 0x7fffu + ((u >> 16) & 1u)) >> 16;
  return (unsigned short)u;
}
__device__ __forceinline__ unsigned f2bf_pk(float a, float b){
  return (unsigned)f2bf(a) | ((unsigned)f2bf(b) << 16);
}

// ---------------------------------------------------------------------------
// K1: proj[h][n][o], ga/gb scores, skip = nodes @ skip_w^T. 16 nodes/block.
// ---------------------------------------------------------------------------
__global__ __launch_bounds__(256) void k_proj(
    const float* __restrict__ nodes, const float* __restrict__ pp,
    const float* __restrict__ ssrc,  const float* __restrict__ stgt,
    const float* __restrict__ skw,
    float* __restrict__ proj, float* __restrict__ ga, float* __restrict__ gb,
    float* __restrict__ skipo)
{
  __shared__ float feat[16][kFI];
  const int tid = threadIdx.x;
  const int n0  = blockIdx.x * 16;
  for (int idx = tid; idx < 16*kFI; idx += 256)
    feat[idx >> 7][idx & 127] = nodes[n0*kFI + idx];
  __syncthreads();
  const int h = tid >> 6, o = tid & 63;
  float accP[16], accS[16];
  #pragma unroll
  for (int n = 0; n < 16; ++n){ accP[n] = 0.f; accS[n] = 0.f; }
  for (int k = 0; k < kFI; ++k){
    const float p = pp[(h*kFI + k)*kFO + o];
    const float w = skw[tid*kFI + k];
    #pragma unroll
    for (int n = 0; n < 16; ++n){
      const float f = feat[n][k];
      accP[n] = fmaf(f, p, accP[n]);
      accS[n] = fmaf(f, w, accS[n]);
    }
  }
  const float sa = ssrc[h*kFO + o];
  const float sb = stgt[h*kFO + o];
  #pragma unroll
  for (int n = 0; n < 16; ++n){
    proj[(h*kN + n0+n)*kFO + o] = accP[n];
    skipo[(n0+n)*kHF + tid]     = accS[n];
    const float va = wave_sum(accP[n] * sa);
    const float vb = wave_sum(accP[n] * sb);
    if (o == 0){ ga[h*kN + n0+n] = va; gb[h*kN + n0+n] = vb; }
  }
}

// ---------------------------------------------------------------------------
// K2: column pass + row LN stats. grid (4 j-tiles, 128 i-strips) x 256 thr.
// S[h][j] = sum_i exp(leaky(a_i+b_j)+m_ij) (unstabilized, safe: scores
// bounded; -1e9 underflows to 0 exactly like the stabilized ref).
// Row stats (sum m, sum m^2) accumulated via wave-reduce + atomics.
// i-loop unrolled 4x with hoisted loads for HBM latency hiding.
// ---------------------------------------------------------------------------
__global__ __launch_bounds__(256) void k_colsum(
    const float* __restrict__ degm, const float* __restrict__ bondm,
    const float* __restrict__ ga,   const float* __restrict__ gb,
    const int* __restrict__ cutp,
    float* __restrict__ S, float* __restrict__ statg,
    float* __restrict__ maskws, int write_mask)
{
  const int j0 = (blockIdx.x * 256 + threadIdx.x) * 4;
  const int lane = threadIdx.x & 63;
  const float cut = (float)cutp[0];
  float4 bv[kH]; f32x4 sv[kH];
  #pragma unroll
  for (int h = 0; h < kH; ++h){
    bv[h] = *(const float4*)&gb[h*kN + j0];
    sv[h] = (f32x4){0.f, 0.f, 0.f, 0.f};
  }
  const int i0 = blockIdx.y * 32;
  for (int ib = 0; ib < 32; ib += 4){
    float4 dg[4], bd[4];
    #pragma unroll
    for (int u = 0; u < 4; ++u){
      const size_t off = (size_t)(i0+ib+u)*kN + j0;
      dg[u] = *(const float4*)&degm[off];
      bd[u] = *(const float4*)&bondm[off];
    }
    #pragma unroll
    for (int u = 0; u < 4; ++u){
      const int i = i0 + ib + u;
      float4 m;
      {
        float w0 = dg[u].x + bd[u].x, w1 = dg[u].y + bd[u].y;
        float w2 = dg[u].z + bd[u].z, w3 = dg[u].w + bd[u].w;
        m.x = w0 > 0.f ? w0 : (bd[u].x > cut ? bd[u].x + w0 : kNegInf);
        m.y = w1 > 0.f ? w1 : (bd[u].y > cut ? bd[u].y + w1 : kNegInf);
        m.z = w2 > 0.f ? w2 : (bd[u].z > cut ? bd[u].z + w2 : kNegInf);
        m.w = w3 > 0.f ? w3 : (bd[u].w > cut ? bd[u].w + w3 : kNegInf);
      }
      if (write_mask) *(float4*)&maskws[(size_t)i*kN + j0] = m;
      // row LN stats
      float rsum = (m.x + m.y) + (m.z + m.w);
      float rsq  = fmaf(m.x, m.x, fmaf(m.y, m.y, fmaf(m.z, m.z, m.w*m.w)));
      rsum = wave_sum(rsum); rsq = wave_sum(rsq);
      if (lane == 0){
        atomicAdd(&statg[2*i+0], rsum);
        atomicAdd(&statg[2*i+1], rsq);
      }
      #pragma unroll
      for (int h = 0; h < kH; ++h){
        const float a = ga[h*kN + i];
        sv[h][0] += __expf(lrelu(a + bv[h].x) + m.x);
        sv[h][1] += __expf(lrelu(a + bv[h].y) + m.y);
        sv[h][2] += __expf(lrelu(a + bv[h].z) + m.z);
        sv[h][3] += __expf(lrelu(a + bv[h].w) + m.w);
      }
    }
  }
  #pragma unroll
  for (int h = 0; h < kH; ++h){
    atomicAdd(&S[h*kN + j0+0], sv[h][0]);
    atomicAdd(&S[h*kN + j0+1], sv[h][1]);
    atomicAdd(&S[h*kN + j0+2], sv[h][2]);
    atomicAdd(&S[h*kN + j0+3], sv[h][3]);
  }
}

// ---------------------------------------------------------------------------
// K2b: finalize LN stats: statg2[i] = (mu, rsqrt(var+eps))
// ---------------------------------------------------------------------------
__global__ __launch_bounds__(256) void k_stat(
    const float* __restrict__ statg, float* __restrict__ statg2)
{
  const int i = blockIdx.x * 256 + threadIdx.x;
  const float mu  = statg[2*i] * (1.f/kN);
  const float var = statg[2*i+1] * (1.f/kN) - mu*mu;
  statg2[2*i+0] = mu;
  statg2[2*i+1] = rsqrtf(var + kLnEps);
}

// ---------------------------------------------------------------------------
// K2c: pack pS = proj/S into bf16 MFMA B-fragment layout:
// pSpack[h][kb][nt][lane][r] = bf16(pS[h][ j=kb*32+(lane>>4)*8+r ][ f=nt*16+(lane&15) ])
// thread t == (((h*128+kb)*4+nt)*64+lane); writes 16B each.
// ---------------------------------------------------------------------------
__global__ __launch_bounds__(256) void k_pack(
    const float* __restrict__ proj, const float* __restrict__ S,
    unsigned short* __restrict__ pSpack)
{
  const int t = blockIdx.x * 256 + threadIdx.x;   // 131072 total
  const int L  = t & 63;
  const int nt = (t >> 6) & 3;
  const int kb = (t >> 8) & 127;
  const int h  = t >> 15;
  const int f  = nt*16 + (L & 15);
  const int jb = kb*32 + (L >> 4)*8;
  union { unsigned short s[8]; uint4 v; } u;
  #pragma unroll
  for (int r = 0; r < 8; ++r){
    const int j = jb + r;
    u.s[r] = f2bf(proj[(size_t)(h*kN + j)*kFO + f] / S[h*kN + j]);
  }
  ((uint4*)pSpack)[t] = u.v;
}

// ---------------------------------------------------------------------------
// K3: aggregation via MFMA. grid (kN/32 row-groups, 4 j-quarters) x 512 thr.
// Per 64-col chunk:
//   phase A: 512 threads compute e=exp(leaky(a+b)+m) for 4 heads x 32 rows,
//            write bf16 pairs into LDS (A-fragment layout, padded), plus
//            write mask_ln inline (stats precomputed by k_colsum/k_stat).
//   phase B: 8 waves = (head, rowgroup); 2 K-steps x 4 n-tiles of
//            mfma_f32_16x16x32_bf16; A from LDS ds_read_b128, B from packed
//            global (L2-resident).
// Partial C merged into accg by float atomics.
// ---------------------------------------------------------------------------
__global__ __launch_bounds__(512) void k_aggr(
    const float* __restrict__ degm, const float* __restrict__ bondm,
    const float* __restrict__ maskws, int have_mask,
    const float* __restrict__ ga, const float* __restrict__ gb,
    const int* __restrict__ cutp,
    const unsigned short* __restrict__ pSpack,
    const float* __restrict__ statg2,
    float* __restrict__ accg, float* __restrict__ mlnp)
{
  __shared__ unsigned short ebuf[kH][32][72];   // 18.4 KB, +8 pad vs 64
  const int tid = threadIdx.x;
  const int w   = tid >> 6;          // 0..7
  const int L   = tid & 63;
  const int h   = w & 3;             // phase-B head
  const int rg  = w >> 2;            // phase-B row group (0/1)
  const int r0  = blockIdx.x * 32;
  const int jq0 = blockIdx.y * 1024;
  const float cut = (float)cutp[0];

  // phase-A mapping: this thread owns j pair (2*jp, 2*jp+1), rows ia, ia+16
  const int jp = tid & 31;
  const int ia = tid >> 5;           // 0..15

  float av[2][kH];
  float mu[2], rs[2];
  #pragma unroll
  for (int p = 0; p < 2; ++p){
    const int i = r0 + p*16 + ia;
    #pragma unroll
    for (int hh = 0; hh < kH; ++hh) av[p][hh] = ga[hh*kN + i];
    mu[p] = statg2[2*i+0];
    rs[p] = statg2[2*i+1];
  }

  f32x4 acc[4];
  #pragma unroll
  for (int nt = 0; nt < 4; ++nt) acc[nt] = (f32x4){0.f,0.f,0.f,0.f};

  for (int c = 0; c < 16; ++c){
    const int jb = jq0 + c*64;
    const int jg = jb + 2*jp;
    // ---- phase A ----
    {
      float2 m2[2];
      if (have_mask){
        #pragma unroll
        for (int p = 0; p < 2; ++p)
          m2[p] = *(const float2*)&maskws[(size_t)(r0 + p*16 + ia)*kN + jg];
      } else {
        #pragma unroll
        for (int p = 0; p < 2; ++p){
          const size_t off = (size_t)(r0 + p*16 + ia)*kN + jg;
          const float2 dg = *(const float2*)&degm[off];
          const float2 bd = *(const float2*)&bondm[off];
          float w0 = dg.x + bd.x, w1 = dg.y + bd.y;
          m2[p].x = w0 > 0.f ? w0 : (bd.x > cut ? bd.x + w0 : kNegInf);
          m2[p].y = w1 > 0.f ? w1 : (bd.y > cut ? bd.y + w1 : kNegInf);
        }
      }
      float2 bv[kH];
      #pragma unroll
      for (int hh = 0; hh < kH; ++hh)
        bv[hh] = *(const float2*)&gb[hh*kN + jg];
      #pragma unroll
      for (int p = 0; p < 2; ++p){
        const int i = p*16 + ia;
        // mask_ln inline
        float2 o;
        o.x = (m2[p].x - mu[p]) * rs[p];
        o.y = (m2[p].y - mu[p]) * rs[p];
        *(float2*)&mlnp[(size_t)(r0+i)*kN + jg] = o;
        #pragma unroll
        for (int hh = 0; hh < kH; ++hh){
          const float e0 = __expf(lrelu(av[p][hh] + bv[hh].x) + m2[p].x);
          const float e1 = __expf(lrelu(av[p][hh] + bv[hh].y) + m2[p].y);
          *(unsigned*)&ebuf[hh][i][2*jp] = f2bf_pk(e0, e1);
        }
      }
    }
    __syncthreads();
    // ---- phase B ----
    {
      const int kb0 = (jb >> 5);
      #pragma unroll
      for (int ks = 0; ks < 2; ++ks){
        const bf16x8 a = *(const bf16x8*)&ebuf[h][rg*16 + (L & 15)][ks*32 + (L >> 4)*8];
        const int kb = kb0 + ks;
        #pragma unroll
        for (int nt = 0; nt < 4; ++nt){
          const bf16x8 b = *(const bf16x8*)&pSpack[(size_t)(((h*128 + kb)*4 + nt)*64 + L)*8];
          acc[nt] = __builtin_amdgcn_mfma_f32_16x16x32_bf16(a, b, acc[nt], 0, 0, 0);
        }
      }
    }
    __syncthreads();
  }

  // epilogue: C/D layout col=lane&15, row=(lane>>4)*4+reg
  #pragma unroll
  for (int nt = 0; nt < 4; ++nt){
    #pragma unroll
    for (int reg = 0; reg < 4; ++reg){
      const int i = r0 + rg*16 + (L >> 4)*4 + reg;
      const int f = h*64 + nt*16 + (L & 15);
      atomicAdd(&accg[(size_t)i*kHF + f], acc[nt][reg]);
    }
  }
}

// ---------------------------------------------------------------------------
// K4: out = elu(acc + skip)
// ---------------------------------------------------------------------------
__global__ __launch_bounds__(256) void k_out(
    const float* __restrict__ accg, const float* __restrict__ skipo,
    float* __restrict__ outp)
{
  const int idx = blockIdx.x * 256 + threadIdx.x;
  float o = accg[idx] + skipo[idx];
  o = o > 0.f ? o : expm1f(o);
  outp[idx] = o;
}

// ---------------------------------------------------------------------------
extern "C" void kernel_launch(void* const* d_in, const int* in_sizes, int n_in,
                              void* d_out, int out_size, void* d_ws, size_t ws_size,
                              hipStream_t stream)
{
  const float* nodes = (const float*)d_in[0];
  const float* degm  = (const float*)d_in[1];
  const float* bondm = (const float*)d_in[3];
  const float* pp    = (const float*)d_in[4];
  const float* ssrc  = (const float*)d_in[5];
  const float* stgt  = (const float*)d_in[6];
  const float* skw   = (const float*)d_in[7];
  const int*   cutp  = (const int*)d_in[8];

  float* ws    = (float*)d_ws;
  float* proj  = ws;                               // H*N*FO = 1,048,576
  float* ga    = proj + (size_t)kH*kN*kFO;         // 16384
  float* gb    = ga + kH*kN;                       // 16384
  float* S     = gb + kH*kN;                       // 16384
  float* skip  = S + kH*kN;                        // N*HF = 1,048,576
  float* accg  = skip + (size_t)kN*kHF;            // N*HF = 1,048,576
  float* statg = accg + (size_t)kN*kHF;            // 2*N
  float* statg2= statg + 2*kN;                     // 2*N
  unsigned short* pSpack = (unsigned short*)(statg2 + 2*kN);  // 1,048,576 bf16
  float* mask  = (float*)(pSpack + (size_t)kH*kN*kFO);        // N*N (optional)

  const size_t base_floats = (size_t)kH*kN*kFO + 3*(size_t)kH*kN
                           + 2*(size_t)kN*kHF + 4*kN
                           + ((size_t)kH*kN*kFO)/2;
  const size_t need_mask = (base_floats + (size_t)kN*kN) * sizeof(float);
  const int have_mask = (ws_size >= need_mask) ? 1 : 0;

  float* outp = (float*)d_out;
  float* mlnp = outp + (size_t)kN*kHF;

  hipMemsetAsync(S, 0, kH*kN*sizeof(float), stream);
  hipMemsetAsync(accg, 0, (size_t)kN*kHF*sizeof(float), stream);
  hipMemsetAsync(statg, 0, 2*kN*sizeof(float), stream);

  k_proj<<<kN/16, 256, 0, stream>>>(nodes, pp, ssrc, stgt, skw, proj, ga, gb, skip);
  k_colsum<<<dim3(kN/1024, kN/32), 256, 0, stream>>>(degm, bondm, ga, gb, cutp,
                                                     S, statg, mask, have_mask);
  k_stat<<<kN/256, 256, 0, stream>>>(statg, statg2);
  k_pack<<<(kH*128*4*64)/256, 256, 0, stream>>>(proj, S, pSpack);
  k_aggr<<<dim3(kN/32, 4), 512, 0, stream>>>(degm, bondm, mask, have_mask,
                                             ga, gb, cutp, pSpack, statg2,
                                             accg, mlnp);
  k_out<<<(kN*kHF)/256, 256, 0, stream>>>(accg, skip, outp);
}